// Round 13
// baseline (49.526 us; speedup 1.0000x reference)
//
#include <hip/hip_runtime.h>

#define B_   4
#define K_   6
#define BK_  (B_ * K_)
#define C_   128
#define C8_  (C_ / 8)         // 16 channel-blocks of 8
#define HF_  32
#define WF_  88
#define P_   (HF_ * WF_)      // 2816 pixels per (b,k) feature map
#define BEV  256
#define NPTS (BEV * BEV)      // 65536
#define CSPLIT 2              // channel slices (grid.z)
#define JPT  (C8_ / CSPLIT)   // 8 channel-blocks (of 8) per thread

typedef _Float16 h2 __attribute__((ext_vector_type(2)));

// pack two f32 into 2xf16 (RNE via v_cvt_f16_f32)
__device__ __forceinline__ unsigned int pkh2(float a, float b) {
    _Float16 ha = (_Float16)a, hb = (_Float16)b;
    unsigned short ua = __builtin_bit_cast(unsigned short, ha);
    unsigned short ub = __builtin_bit_cast(unsigned short, hb);
    return (unsigned int)ua | ((unsigned int)ub << 16);
}
__device__ __forceinline__ h2 dup2(float a) {
    _Float16 ha = (_Float16)a;
    h2 r; r[0] = ha; r[1] = ha; return r;
}
__device__ __forceinline__ float fdot2u(h2 pk, unsigned int w, float acc) {
    return __builtin_amdgcn_fdot2(pk, __builtin_bit_cast(h2, w), acc, false);
}
__device__ __forceinline__ h2 ash2(unsigned int u) { return __builtin_bit_cast(h2, u); }

#define ONE_LO 0x00003C00u   // half2 (1,0)
#define ONE_HI 0x3C000000u   // half2 (0,1)

// ---------------------------------------------------------------------------
// Kernel 1: shuffle features [BK, C, P] (f32) -> [BK, C/8, P, 8] packed f16.
// 16 B per (pixel, 8-channel block): one aligned uint4 gather = 8 channels.
// ---------------------------------------------------------------------------
__global__ __launch_bounds__(256) void shuffle_feat_f16(
    const float* __restrict__ in, uint4* __restrict__ outT)
{
    __shared__ float lds[64][C_ + 1];
    const int bk  = blockIdx.y;
    const int p0  = blockIdx.x * 64;
    const int tid = threadIdx.x;

    const int pl = tid & 63;        // pixel within tile
    const int cq = tid >> 6;        // 0..3 channel sub-lane (read phase)
    const float* src = in + (size_t)bk * C_ * P_;
#pragma unroll
    for (int c0 = 0; c0 < C_; c0 += 4) {
        const int c = c0 + cq;
        lds[pl][c] = src[(size_t)c * P_ + p0 + pl];
    }
    __syncthreads();

    // write phase: pack 8 channels of one pixel into 16 B; lanes over pixels
    uint4* dst = outT + (size_t)bk * C8_ * P_;
    const int cbq = tid >> 6;       // 0..3 cb sub-lane
#pragma unroll
    for (int cb0 = 0; cb0 < C8_; cb0 += 4) {
        const int cb = cb0 + cbq;
        const float* row = &lds[pl][cb * 8];
        uint4 q;
        q.x = pkh2(row[0], row[1]);
        q.y = pkh2(row[2], row[3]);
        q.z = pkh2(row[4], row[5]);
        q.w = pkh2(row[6], row[7]);
        dst[(size_t)cb * P_ + p0 + pl] = q;
    }
}

// ---------------------------------------------------------------------------
// Kernel 2: per-BEV-point projection + bilinear sampling over 6 cameras.
// Grid: (256 32x8-tiles, B, CSPLIT); block 256 = one 32x8 BEV tile (wave =
// 32x2). __launch_bounds__(256,5): cap VGPR ~102 to lift occupancy to
// 5 waves/SIMD (probe: is register-pressure-limited TLP the latency stall?).
// ---------------------------------------------------------------------------
template <bool TRANS>
__global__ __launch_bounds__(256, 5) void bev_project(
    const void* __restrict__ featv,
    const float* __restrict__ intr,   // [B,K,3,3]
    const float* __restrict__ extr,   // [B,K,4,4]
    float* __restrict__ out)          // [B,C,BEV,BEV]
{
    const int tid = threadIdx.x;
    const int ix  = (blockIdx.x & 7) * 32 + (tid & 31);
    const int iy  = (blockIdx.x >> 3) * 8 + (tid >> 5);
    const int b   = blockIdx.y;
    const int cs  = blockIdx.z;

    const float STEP = 102.4f / 255.0f;
    const float gx = -51.2f + ix * STEP;
    const float gy = -51.2f + iy * STEP;

    int   off[K_], dX[K_], dY[K_];
    h2    w00h[K_], w01h[K_], w10h[K_], w11h[K_];
    bool  val[K_];
    float w00[K_], w01[K_], w10[K_], w11[K_];
    float cnt = 0.0f;

#pragma unroll
    for (int k = 0; k < K_; ++k) {
        const float* E = extr + (size_t)(b * K_ + k) * 16;
        const float* I = intr + (size_t)(b * K_ + k) * 9;
        // world z = 0, w = 1
        const float c0 = E[0] * gx + E[1] * gy + E[3];
        const float c1 = E[4] * gx + E[5] * gy + E[7];
        const float c2 = E[8] * gx + E[9] * gy + E[11];
        const float uu = I[0] * c0 + I[1] * c1 + I[2] * c2;
        const float vv = I[3] * c0 + I[4] * c1 + I[5] * c2;
        const float ww = I[6] * c0 + I[7] * c1 + I[8] * c2;
        const float depth = fmaxf(ww, 1e-5f);
        const float u = uu / depth * 0.125f;   // sx = 88/704
        const float v = vv / depth * 0.125f;   // sy = 32/256
        const bool valid = (ww > 1e-3f) && (u >= 0.0f) && (u <= (float)(WF_ - 1))
                                        && (v >= 0.0f) && (v <= (float)(HF_ - 1));
        const float uc = fminf(fmaxf(u, 0.0f), (float)(WF_ - 1));
        const float vc = fminf(fmaxf(v, 0.0f), (float)(HF_ - 1));
        const float x0f = floorf(uc), y0f = floorf(vc);
        const int x0 = (int)x0f, y0 = (int)y0f;
        const int x1 = min(x0 + 1, WF_ - 1), y1 = min(y0 + 1, HF_ - 1);
        const float wx = uc - x0f, wy = vc - y0f;

        val[k] = valid;
        cnt += valid ? 1.0f : 0.0f;
        w00[k] = (1.0f - wx) * (1.0f - wy);
        w01[k] = wx * (1.0f - wy);
        w10[k] = (1.0f - wx) * wy;
        w11[k] = wx * wy;

        const int pix = y0 * WF_ + x0;
        if (TRANS) {
            off[k] = ((b * K_ + k) * C8_ * P_ + pix) * 16;  // byte offset
            dX[k]  = (x1 - x0) * 16;                        // bytes
            dY[k]  = (y1 - y0) * (WF_ * 16);                // bytes
        } else {
            off[k] = (b * K_ + k) * (C_ * P_) + pix;
            dX[k]  = (x1 - x0);
            dY[k]  = (y1 - y0) * WF_;
        }
    }

    const float inv = 1.0f / fmaxf(cnt, 1.0f);
#pragma unroll
    for (int k = 0; k < K_; ++k) {       // fold 1/count, duplicate as half2
        w00[k] *= inv; w01[k] *= inv; w10[k] *= inv; w11[k] *= inv;
        w00h[k] = dup2(w00[k]);
        w01h[k] = dup2(w01[k]);
        w10h[k] = dup2(w10[k]);
        w11h[k] = dup2(w11[k]);
    }

    float* outp = out + (size_t)b * C_ * NPTS + (size_t)(cs * JPT * 8) * NPTS
                      + (size_t)iy * BEV + ix;

    if (TRANS) {
        const char* bp[K_];
#pragma unroll
        for (int k = 0; k < K_; ++k)
            bp[k] = (const char*)featv + off[k] + (size_t)(cs * JPT) * (P_ * 16);

#pragma unroll 1
        for (int j = 0; j < JPT; ++j) {
            float a0 = 0.0f, a1 = 0.0f, a2 = 0.0f, a3 = 0.0f;
            float a4 = 0.0f, a5 = 0.0f, a6 = 0.0f, a7 = 0.0f;
#pragma unroll
            for (int k = 0; k < K_; ++k) {
                if (!val[k]) continue;
                const char* pb = bp[k] + j * (P_ * 16);
                const uint4 q00 = *(const uint4*)(pb);
                const uint4 q01 = *(const uint4*)(pb + dX[k]);
                const uint4 q10 = *(const uint4*)(pb + dY[k]);
                const uint4 q11 = *(const uint4*)(pb + dX[k] + dY[k]);
                const h2 wa = w00h[k], wb = w01h[k], wc = w10h[k], wd = w11h[k];
                // channels 0,1  (.x): 4 pk_fma + 2 dot2 extracts
                h2 t = ash2(q00.x) * wa;
                t = __builtin_elementwise_fma(ash2(q01.x), wb, t);
                t = __builtin_elementwise_fma(ash2(q10.x), wc, t);
                t = __builtin_elementwise_fma(ash2(q11.x), wd, t);
                a0 = fdot2u(t, ONE_LO, a0);
                a1 = fdot2u(t, ONE_HI, a1);
                // channels 2,3  (.y)
                t = ash2(q00.y) * wa;
                t = __builtin_elementwise_fma(ash2(q01.y), wb, t);
                t = __builtin_elementwise_fma(ash2(q10.y), wc, t);
                t = __builtin_elementwise_fma(ash2(q11.y), wd, t);
                a2 = fdot2u(t, ONE_LO, a2);
                a3 = fdot2u(t, ONE_HI, a3);
                // channels 4,5  (.z)
                t = ash2(q00.z) * wa;
                t = __builtin_elementwise_fma(ash2(q01.z), wb, t);
                t = __builtin_elementwise_fma(ash2(q10.z), wc, t);
                t = __builtin_elementwise_fma(ash2(q11.z), wd, t);
                a4 = fdot2u(t, ONE_LO, a4);
                a5 = fdot2u(t, ONE_HI, a5);
                // channels 6,7  (.w)
                t = ash2(q00.w) * wa;
                t = __builtin_elementwise_fma(ash2(q01.w), wb, t);
                t = __builtin_elementwise_fma(ash2(q10.w), wc, t);
                t = __builtin_elementwise_fma(ash2(q11.w), wd, t);
                a6 = fdot2u(t, ONE_LO, a6);
                a7 = fdot2u(t, ONE_HI, a7);
            }
            __builtin_nontemporal_store(a0, &outp[(size_t)(j * 8 + 0) * NPTS]);
            __builtin_nontemporal_store(a1, &outp[(size_t)(j * 8 + 1) * NPTS]);
            __builtin_nontemporal_store(a2, &outp[(size_t)(j * 8 + 2) * NPTS]);
            __builtin_nontemporal_store(a3, &outp[(size_t)(j * 8 + 3) * NPTS]);
            __builtin_nontemporal_store(a4, &outp[(size_t)(j * 8 + 4) * NPTS]);
            __builtin_nontemporal_store(a5, &outp[(size_t)(j * 8 + 5) * NPTS]);
            __builtin_nontemporal_store(a6, &outp[(size_t)(j * 8 + 6) * NPTS]);
            __builtin_nontemporal_store(a7, &outp[(size_t)(j * 8 + 7) * NPTS]);
        }
    } else {
        const float* feat = (const float*)featv;
#pragma unroll 1
        for (int c = 0; c < JPT * 8; ++c) {
            float a = 0.0f;
#pragma unroll
            for (int k = 0; k < K_; ++k) {
                if (!val[k]) continue;
                const float* pb = feat + off[k] + (size_t)(cs * JPT * 8 + c) * P_;
                a += w00[k] * pb[0] + w01[k] * pb[dX[k]]
                   + w10[k] * pb[dY[k]] + w11[k] * pb[dX[k] + dY[k]];
            }
            __builtin_nontemporal_store(a, &outp[(size_t)c * NPTS]);
        }
    }
}

extern "C" void kernel_launch(void* const* d_in, const int* in_sizes, int n_in,
                              void* d_out, int out_size, void* d_ws, size_t ws_size,
                              hipStream_t stream) {
    const float* features   = (const float*)d_in[0];
    const float* intrinsics = (const float*)d_in[1];
    const float* extrinsics = (const float*)d_in[2];
    float* out = (float*)d_out;

    const size_t need = sizeof(uint4) * (size_t)BK_ * C8_ * P_;  // ~17 MB
    if (ws_size >= need) {
        uint4* featT = (uint4*)d_ws;
        shuffle_feat_f16<<<dim3(P_ / 64, BK_), 256, 0, stream>>>(features, featT);
        bev_project<true><<<dim3(256, B_, CSPLIT), 256, 0, stream>>>(
            (const void*)featT, intrinsics, extrinsics, out);
    } else {
        bev_project<false><<<dim3(256, B_, CSPLIT), 256, 0, stream>>>(
            (const void*)features, intrinsics, extrinsics, out);
    }
}

// Round 14
// 47.513 us; speedup vs baseline: 1.0424x; 1.0424x over previous
//
#include <hip/hip_runtime.h>

#define B_   4
#define K_   6
#define BK_  (B_ * K_)
#define C_   128
#define C8_  (C_ / 8)         // 16 channel-blocks of 8
#define HF_  32
#define WF_  88
#define P_   (HF_ * WF_)      // 2816 pixels per (b,k) feature map
#define BEV  256
#define NPTS (BEV * BEV)      // 65536
#define CSPLIT 2              // channel slices (grid.z)
#define JPT  (C8_ / CSPLIT)   // 8 channel-blocks (of 8) per thread

typedef _Float16 h2 __attribute__((ext_vector_type(2)));

__device__ __forceinline__ unsigned int pkh2(float a, float b) {
    _Float16 ha = (_Float16)a, hb = (_Float16)b;
    unsigned short ua = __builtin_bit_cast(unsigned short, ha);
    unsigned short ub = __builtin_bit_cast(unsigned short, hb);
    return (unsigned int)ua | ((unsigned int)ub << 16);
}
__device__ __forceinline__ h2 dup2(float a) {
    _Float16 ha = (_Float16)a;
    h2 r; r[0] = ha; r[1] = ha; return r;
}
__device__ __forceinline__ float fdot2u(h2 pk, unsigned int w, float acc) {
    return __builtin_amdgcn_fdot2(pk, __builtin_bit_cast(h2, w), acc, false);
}
__device__ __forceinline__ h2 ash2(unsigned int u) { return __builtin_bit_cast(h2, u); }

#define ONE_LO 0x00003C00u   // half2 (1,0)
#define ONE_HI 0x3C000000u   // half2 (0,1)

// ---------------------------------------------------------------------------
// Kernel 1: shuffle features [BK, C, P] (f32) -> [BK, C/8, P, 8] packed f16.
// ---------------------------------------------------------------------------
__global__ __launch_bounds__(256) void shuffle_feat_f16(
    const float* __restrict__ in, uint4* __restrict__ outT)
{
    __shared__ float lds[64][C_ + 1];
    const int bk  = blockIdx.y;
    const int p0  = blockIdx.x * 64;
    const int tid = threadIdx.x;

    const int pl = tid & 63;        // pixel within tile
    const int cq = tid >> 6;        // 0..3 channel sub-lane (read phase)
    const float* src = in + (size_t)bk * C_ * P_;
#pragma unroll
    for (int c0 = 0; c0 < C_; c0 += 4) {
        const int c = c0 + cq;
        lds[pl][c] = src[(size_t)c * P_ + p0 + pl];
    }
    __syncthreads();

    uint4* dst = outT + (size_t)bk * C8_ * P_;
    const int cbq = tid >> 6;       // 0..3 cb sub-lane
#pragma unroll
    for (int cb0 = 0; cb0 < C8_; cb0 += 4) {
        const int cb = cb0 + cbq;
        const float* row = &lds[pl][cb * 8];
        uint4 q;
        q.x = pkh2(row[0], row[1]);
        q.y = pkh2(row[2], row[3]);
        q.z = pkh2(row[4], row[5]);
        q.w = pkh2(row[6], row[7]);
        dst[(size_t)cb * P_ + p0 + pl] = q;
    }
}

// ---------------------------------------------------------------------------
// Kernel 2: projection + bilinear sampling over 6 cameras.
// Block = 32x8 BEV tile, 4 waves laid out as 8x8 patches (gather phase):
// isotropic patch minimizes u/v pixel span per wave for every camera yaw
// -> ~2x fewer 128-B lines moved L2->L1 per gather (the dominant cost).
// Stores re-mapped through padded LDS so lanes run ix-major across the full
// 32-wide tile -> full 128-B store lines (what 16x4 tiles in R8 lost).
// ---------------------------------------------------------------------------
template <bool TRANS>
__global__ __launch_bounds__(256) void bev_project(
    const void* __restrict__ featv,
    const float* __restrict__ intr,   // [B,K,3,3]
    const float* __restrict__ extr,   // [B,K,4,4]
    float* __restrict__ out)          // [B,C,BEV,BEV]
{
    __shared__ float sbuf[8 * 32 * 9];   // [iy][ix][8ch + pad] stride 9: conflict-free
    const int tid = threadIdx.x;
    const int ix0 = (blockIdx.x & 7) * 32;
    const int iy0 = (blockIdx.x >> 3) * 8;
    // gather mapping: wave (tid>>6) owns an 8x8 patch
    const int gxq = ((tid & 63) & 7) + (tid >> 6) * 8;   // 0..31 tile-local x
    const int gyq = (tid & 63) >> 3;                     // 0..7  tile-local y
    const int ix  = ix0 + gxq;
    const int iy  = iy0 + gyq;
    const int b   = blockIdx.y;
    const int cs  = blockIdx.z;

    const float STEP = 102.4f / 255.0f;
    const float gx = -51.2f + ix * STEP;
    const float gy = -51.2f + iy * STEP;

    int   off[K_], dX[K_], dY[K_];
    h2    w00h[K_], w01h[K_], w10h[K_], w11h[K_];
    bool  val[K_];
    float w00[K_], w01[K_], w10[K_], w11[K_];
    float cnt = 0.0f;

#pragma unroll
    for (int k = 0; k < K_; ++k) {
        const float* E = extr + (size_t)(b * K_ + k) * 16;
        const float* I = intr + (size_t)(b * K_ + k) * 9;
        // world z = 0, w = 1
        const float c0 = E[0] * gx + E[1] * gy + E[3];
        const float c1 = E[4] * gx + E[5] * gy + E[7];
        const float c2 = E[8] * gx + E[9] * gy + E[11];
        const float uu = I[0] * c0 + I[1] * c1 + I[2] * c2;
        const float vv = I[3] * c0 + I[4] * c1 + I[5] * c2;
        const float ww = I[6] * c0 + I[7] * c1 + I[8] * c2;
        const float depth = fmaxf(ww, 1e-5f);
        const float u = uu / depth * 0.125f;   // sx = 88/704
        const float v = vv / depth * 0.125f;   // sy = 32/256
        const bool valid = (ww > 1e-3f) && (u >= 0.0f) && (u <= (float)(WF_ - 1))
                                        && (v >= 0.0f) && (v <= (float)(HF_ - 1));
        const float uc = fminf(fmaxf(u, 0.0f), (float)(WF_ - 1));
        const float vc = fminf(fmaxf(v, 0.0f), (float)(HF_ - 1));
        const float x0f = floorf(uc), y0f = floorf(vc);
        const int x0 = (int)x0f, y0 = (int)y0f;
        const int x1 = min(x0 + 1, WF_ - 1), y1 = min(y0 + 1, HF_ - 1);
        const float wx = uc - x0f, wy = vc - y0f;

        val[k] = valid;
        cnt += valid ? 1.0f : 0.0f;
        w00[k] = (1.0f - wx) * (1.0f - wy);
        w01[k] = wx * (1.0f - wy);
        w10[k] = (1.0f - wx) * wy;
        w11[k] = wx * wy;

        const int pix = y0 * WF_ + x0;
        if (TRANS) {
            off[k] = ((b * K_ + k) * C8_ * P_ + pix) * 16;  // byte offset
            dX[k]  = (x1 - x0) * 16;                        // bytes
            dY[k]  = (y1 - y0) * (WF_ * 16);                // bytes
        } else {
            off[k] = (b * K_ + k) * (C_ * P_) + pix;
            dX[k]  = (x1 - x0);
            dY[k]  = (y1 - y0) * WF_;
        }
    }

    const float inv = 1.0f / fmaxf(cnt, 1.0f);
#pragma unroll
    for (int k = 0; k < K_; ++k) {
        w00[k] *= inv; w01[k] *= inv; w10[k] *= inv; w11[k] *= inv;
        w00h[k] = dup2(w00[k]);
        w01h[k] = dup2(w01[k]);
        w10h[k] = dup2(w10[k]);
        w11h[k] = dup2(w11[k]);
    }

    // store mapping: lanes ix-major across the full 32-wide tile
    const int sx = tid & 31, sy = tid >> 5;
    float* outp = out + (size_t)b * C_ * NPTS + (size_t)(cs * JPT * 8) * NPTS
                      + (size_t)(iy0 + sy) * BEV + ix0 + sx;
    float* sb = &sbuf[(gyq * 32 + gxq) * 9];
    const float* rb = &sbuf[(sy * 32 + sx) * 9];

    if (TRANS) {
        const char* bp[K_];
#pragma unroll
        for (int k = 0; k < K_; ++k)
            bp[k] = (const char*)featv + off[k] + (size_t)(cs * JPT) * (P_ * 16);

#pragma unroll 1
        for (int j = 0; j < JPT; ++j) {
            float a0 = 0.0f, a1 = 0.0f, a2 = 0.0f, a3 = 0.0f;
            float a4 = 0.0f, a5 = 0.0f, a6 = 0.0f, a7 = 0.0f;
#pragma unroll
            for (int k = 0; k < K_; ++k) {
                if (!val[k]) continue;
                const char* pb = bp[k] + j * (P_ * 16);
                const uint4 q00 = *(const uint4*)(pb);
                const uint4 q01 = *(const uint4*)(pb + dX[k]);
                const uint4 q10 = *(const uint4*)(pb + dY[k]);
                const uint4 q11 = *(const uint4*)(pb + dX[k] + dY[k]);
                const h2 wa = w00h[k], wb = w01h[k], wc = w10h[k], wd = w11h[k];
                h2 t = ash2(q00.x) * wa;
                t = __builtin_elementwise_fma(ash2(q01.x), wb, t);
                t = __builtin_elementwise_fma(ash2(q10.x), wc, t);
                t = __builtin_elementwise_fma(ash2(q11.x), wd, t);
                a0 = fdot2u(t, ONE_LO, a0);
                a1 = fdot2u(t, ONE_HI, a1);
                t = ash2(q00.y) * wa;
                t = __builtin_elementwise_fma(ash2(q01.y), wb, t);
                t = __builtin_elementwise_fma(ash2(q10.y), wc, t);
                t = __builtin_elementwise_fma(ash2(q11.y), wd, t);
                a2 = fdot2u(t, ONE_LO, a2);
                a3 = fdot2u(t, ONE_HI, a3);
                t = ash2(q00.z) * wa;
                t = __builtin_elementwise_fma(ash2(q01.z), wb, t);
                t = __builtin_elementwise_fma(ash2(q10.z), wc, t);
                t = __builtin_elementwise_fma(ash2(q11.z), wd, t);
                a4 = fdot2u(t, ONE_LO, a4);
                a5 = fdot2u(t, ONE_HI, a5);
                t = ash2(q00.w) * wa;
                t = __builtin_elementwise_fma(ash2(q01.w), wb, t);
                t = __builtin_elementwise_fma(ash2(q10.w), wc, t);
                t = __builtin_elementwise_fma(ash2(q11.w), wd, t);
                a6 = fdot2u(t, ONE_LO, a6);
                a7 = fdot2u(t, ONE_HI, a7);
            }
            // stage in LDS, re-emit with ix-major lanes (full 128-B lines)
            sb[0] = a0; sb[1] = a1; sb[2] = a2; sb[3] = a3;
            sb[4] = a4; sb[5] = a5; sb[6] = a6; sb[7] = a7;
            __syncthreads();
#pragma unroll
            for (int c = 0; c < 8; ++c)
                __builtin_nontemporal_store(rb[c], &outp[(size_t)(j * 8 + c) * NPTS]);
            __syncthreads();
        }
    } else {
        const float* feat = (const float*)featv;
#pragma unroll 1
        for (int c = 0; c < JPT * 8; ++c) {
            float a = 0.0f;
#pragma unroll
            for (int k = 0; k < K_; ++k) {
                if (!val[k]) continue;
                const float* pb = feat + off[k] + (size_t)(cs * JPT * 8 + c) * P_;
                a += w00[k] * pb[0] + w01[k] * pb[dX[k]]
                   + w10[k] * pb[dY[k]] + w11[k] * pb[dX[k] + dY[k]];
            }
            __builtin_nontemporal_store(a, &outp[(size_t)c * NPTS]);
        }
    }
}

extern "C" void kernel_launch(void* const* d_in, const int* in_sizes, int n_in,
                              void* d_out, int out_size, void* d_ws, size_t ws_size,
                              hipStream_t stream) {
    const float* features   = (const float*)d_in[0];
    const float* intrinsics = (const float*)d_in[1];
    const float* extrinsics = (const float*)d_in[2];
    float* out = (float*)d_out;

    const size_t need = sizeof(uint4) * (size_t)BK_ * C8_ * P_;  // ~17 MB
    if (ws_size >= need) {
        uint4* featT = (uint4*)d_ws;
        shuffle_feat_f16<<<dim3(P_ / 64, BK_), 256, 0, stream>>>(features, featT);
        bev_project<true><<<dim3(256, B_, CSPLIT), 256, 0, stream>>>(
            (const void*)featT, intrinsics, extrinsics, out);
    } else {
        bev_project<false><<<dim3(256, B_, CSPLIT), 256, 0, stream>>>(
            (const void*)features, intrinsics, extrinsics, out);
    }
}

// Round 15
// 47.385 us; speedup vs baseline: 1.0452x; 1.0027x over previous
//
#include <hip/hip_runtime.h>

#define B_   4
#define K_   6
#define BK_  (B_ * K_)
#define C_   128
#define C8_  (C_ / 8)         // 16 channel-blocks of 8
#define HF_  32
#define WF_  88
#define P_   (HF_ * WF_)      // 2816 pixels per (b,k) feature map
#define BEV  256
#define NPTS (BEV * BEV)      // 65536
#define CSPLIT 2              // channel slices (grid.z)
#define JPT  (C8_ / CSPLIT)   // 8 channel-blocks (of 8) per thread

typedef _Float16 h2 __attribute__((ext_vector_type(2)));

__device__ __forceinline__ unsigned int pkh2(float a, float b) {
    _Float16 ha = (_Float16)a, hb = (_Float16)b;
    unsigned short ua = __builtin_bit_cast(unsigned short, ha);
    unsigned short ub = __builtin_bit_cast(unsigned short, hb);
    return (unsigned int)ua | ((unsigned int)ub << 16);
}
__device__ __forceinline__ h2 dup2(float a) {
    _Float16 ha = (_Float16)a;
    h2 r; r[0] = ha; r[1] = ha; return r;
}
__device__ __forceinline__ float fdot2u(h2 pk, unsigned int w, float acc) {
    return __builtin_amdgcn_fdot2(pk, __builtin_bit_cast(h2, w), acc, false);
}
__device__ __forceinline__ h2 ash2(unsigned int u) { return __builtin_bit_cast(h2, u); }

#define ONE_LO 0x00003C00u   // half2 (1,0)
#define ONE_HI 0x3C000000u   // half2 (0,1)

// ---------------------------------------------------------------------------
// Kernel 1: shuffle features [BK, C, P] (f32) -> [BK, C/8, P, 8] packed f16.
// ---------------------------------------------------------------------------
__global__ __launch_bounds__(256) void shuffle_feat_f16(
    const float* __restrict__ in, uint4* __restrict__ outT)
{
    __shared__ float lds[64][C_ + 1];
    const int bk  = blockIdx.y;
    const int p0  = blockIdx.x * 64;
    const int tid = threadIdx.x;

    const int pl = tid & 63;        // pixel within tile
    const int cq = tid >> 6;        // 0..3 channel sub-lane (read phase)
    const float* src = in + (size_t)bk * C_ * P_;
#pragma unroll
    for (int c0 = 0; c0 < C_; c0 += 4) {
        const int c = c0 + cq;
        lds[pl][c] = src[(size_t)c * P_ + p0 + pl];
    }
    __syncthreads();

    uint4* dst = outT + (size_t)bk * C8_ * P_;
    const int cbq = tid >> 6;       // 0..3 cb sub-lane
#pragma unroll
    for (int cb0 = 0; cb0 < C8_; cb0 += 4) {
        const int cb = cb0 + cbq;
        const float* row = &lds[pl][cb * 8];
        uint4 q;
        q.x = pkh2(row[0], row[1]);
        q.y = pkh2(row[2], row[3]);
        q.z = pkh2(row[4], row[5]);
        q.w = pkh2(row[6], row[7]);
        dst[(size_t)cb * P_ + p0 + pl] = q;
    }
}

// ---------------------------------------------------------------------------
// Kernel 2: projection + bilinear sampling over 6 cameras.
// Block = 32x8 BEV tile; gather phase: 4 waves as 8x8 patches (isotropic
// pixel span -> min cache lines); store phase: lanes ix-major (full 128-B
// lines). Double-buffered LDS staging + deferred stores: ONE barrier per
// j-iteration (was 2), and stores of j-1 issue before gathers of j so the
// store drain overlaps gather latency.
// ---------------------------------------------------------------------------
template <bool TRANS>
__global__ __launch_bounds__(256) void bev_project(
    const void* __restrict__ featv,
    const float* __restrict__ intr,   // [B,K,3,3]
    const float* __restrict__ extr,   // [B,K,4,4]
    float* __restrict__ out)          // [B,C,BEV,BEV]
{
    __shared__ float sbuf[2][8 * 32 * 9];   // [buf][iy][ix][8ch+pad] stride 9
    const int tid = threadIdx.x;
    const int ix0 = (blockIdx.x & 7) * 32;
    const int iy0 = (blockIdx.x >> 3) * 8;
    // gather mapping: wave (tid>>6) owns an 8x8 patch
    const int gxq = ((tid & 63) & 7) + (tid >> 6) * 8;   // 0..31 tile-local x
    const int gyq = (tid & 63) >> 3;                     // 0..7  tile-local y
    const int ix  = ix0 + gxq;
    const int iy  = iy0 + gyq;
    const int b   = blockIdx.y;
    const int cs  = blockIdx.z;

    const float STEP = 102.4f / 255.0f;
    const float gx = -51.2f + ix * STEP;
    const float gy = -51.2f + iy * STEP;

    int   off[K_], dX[K_], dY[K_];
    h2    w00h[K_], w01h[K_], w10h[K_], w11h[K_];
    bool  val[K_];
    float w00[K_], w01[K_], w10[K_], w11[K_];
    float cnt = 0.0f;

#pragma unroll
    for (int k = 0; k < K_; ++k) {
        const float* E = extr + (size_t)(b * K_ + k) * 16;
        const float* I = intr + (size_t)(b * K_ + k) * 9;
        // world z = 0, w = 1
        const float c0 = E[0] * gx + E[1] * gy + E[3];
        const float c1 = E[4] * gx + E[5] * gy + E[7];
        const float c2 = E[8] * gx + E[9] * gy + E[11];
        const float uu = I[0] * c0 + I[1] * c1 + I[2] * c2;
        const float vv = I[3] * c0 + I[4] * c1 + I[5] * c2;
        const float ww = I[6] * c0 + I[7] * c1 + I[8] * c2;
        const float depth = fmaxf(ww, 1e-5f);
        const float u = uu / depth * 0.125f;   // sx = 88/704
        const float v = vv / depth * 0.125f;   // sy = 32/256
        const bool valid = (ww > 1e-3f) && (u >= 0.0f) && (u <= (float)(WF_ - 1))
                                        && (v >= 0.0f) && (v <= (float)(HF_ - 1));
        const float uc = fminf(fmaxf(u, 0.0f), (float)(WF_ - 1));
        const float vc = fminf(fmaxf(v, 0.0f), (float)(HF_ - 1));
        const float x0f = floorf(uc), y0f = floorf(vc);
        const int x0 = (int)x0f, y0 = (int)y0f;
        const int x1 = min(x0 + 1, WF_ - 1), y1 = min(y0 + 1, HF_ - 1);
        const float wx = uc - x0f, wy = vc - y0f;

        val[k] = valid;
        cnt += valid ? 1.0f : 0.0f;
        w00[k] = (1.0f - wx) * (1.0f - wy);
        w01[k] = wx * (1.0f - wy);
        w10[k] = (1.0f - wx) * wy;
        w11[k] = wx * wy;

        const int pix = y0 * WF_ + x0;
        if (TRANS) {
            off[k] = ((b * K_ + k) * C8_ * P_ + pix) * 16;  // byte offset
            dX[k]  = (x1 - x0) * 16;                        // bytes
            dY[k]  = (y1 - y0) * (WF_ * 16);                // bytes
        } else {
            off[k] = (b * K_ + k) * (C_ * P_) + pix;
            dX[k]  = (x1 - x0);
            dY[k]  = (y1 - y0) * WF_;
        }
    }

    const float inv = 1.0f / fmaxf(cnt, 1.0f);
#pragma unroll
    for (int k = 0; k < K_; ++k) {
        w00[k] *= inv; w01[k] *= inv; w10[k] *= inv; w11[k] *= inv;
        w00h[k] = dup2(w00[k]);
        w01h[k] = dup2(w01[k]);
        w10h[k] = dup2(w10[k]);
        w11h[k] = dup2(w11[k]);
    }

    // store mapping: lanes ix-major across the full 32-wide tile
    const int sx = tid & 31, sy = tid >> 5;
    float* outp = out + (size_t)b * C_ * NPTS + (size_t)(cs * JPT * 8) * NPTS
                      + (size_t)(iy0 + sy) * BEV + ix0 + sx;
    const int sb_off = (gyq * 32 + gxq) * 9;
    const int rb_off = (sy * 32 + sx) * 9;

    if (TRANS) {
        const char* bp[K_];
#pragma unroll
        for (int k = 0; k < K_; ++k)
            bp[k] = (const char*)featv + off[k] + (size_t)(cs * JPT) * (P_ * 16);

#pragma unroll 1
        for (int j = 0; j < JPT; ++j) {
            // deferred store phase: emit j-1's tile (overlaps j's gathers)
            if (j > 0) {
                const float* rb = &sbuf[(j - 1) & 1][rb_off];
#pragma unroll
                for (int c = 0; c < 8; ++c)
                    __builtin_nontemporal_store(
                        rb[c], &outp[(size_t)((j - 1) * 8 + c) * NPTS]);
            }

            float a0 = 0.0f, a1 = 0.0f, a2 = 0.0f, a3 = 0.0f;
            float a4 = 0.0f, a5 = 0.0f, a6 = 0.0f, a7 = 0.0f;
#pragma unroll
            for (int k = 0; k < K_; ++k) {
                if (!val[k]) continue;
                const char* pb = bp[k] + j * (P_ * 16);
                const uint4 q00 = *(const uint4*)(pb);
                const uint4 q01 = *(const uint4*)(pb + dX[k]);
                const uint4 q10 = *(const uint4*)(pb + dY[k]);
                const uint4 q11 = *(const uint4*)(pb + dX[k] + dY[k]);
                const h2 wa = w00h[k], wb = w01h[k], wc = w10h[k], wd = w11h[k];
                h2 t = ash2(q00.x) * wa;
                t = __builtin_elementwise_fma(ash2(q01.x), wb, t);
                t = __builtin_elementwise_fma(ash2(q10.x), wc, t);
                t = __builtin_elementwise_fma(ash2(q11.x), wd, t);
                a0 = fdot2u(t, ONE_LO, a0);
                a1 = fdot2u(t, ONE_HI, a1);
                t = ash2(q00.y) * wa;
                t = __builtin_elementwise_fma(ash2(q01.y), wb, t);
                t = __builtin_elementwise_fma(ash2(q10.y), wc, t);
                t = __builtin_elementwise_fma(ash2(q11.y), wd, t);
                a2 = fdot2u(t, ONE_LO, a2);
                a3 = fdot2u(t, ONE_HI, a3);
                t = ash2(q00.z) * wa;
                t = __builtin_elementwise_fma(ash2(q01.z), wb, t);
                t = __builtin_elementwise_fma(ash2(q10.z), wc, t);
                t = __builtin_elementwise_fma(ash2(q11.z), wd, t);
                a4 = fdot2u(t, ONE_LO, a4);
                a5 = fdot2u(t, ONE_HI, a5);
                t = ash2(q00.w) * wa;
                t = __builtin_elementwise_fma(ash2(q01.w), wb, t);
                t = __builtin_elementwise_fma(ash2(q10.w), wc, t);
                t = __builtin_elementwise_fma(ash2(q11.w), wd, t);
                a6 = fdot2u(t, ONE_LO, a6);
                a7 = fdot2u(t, ONE_HI, a7);
            }
            float* sb = &sbuf[j & 1][sb_off];
            sb[0] = a0; sb[1] = a1; sb[2] = a2; sb[3] = a3;
            sb[4] = a4; sb[5] = a5; sb[6] = a6; sb[7] = a7;
            __syncthreads();   // one barrier per iteration (double-buffered)
        }
        // epilogue: store last tile
        {
            const float* rb = &sbuf[(JPT - 1) & 1][rb_off];
#pragma unroll
            for (int c = 0; c < 8; ++c)
                __builtin_nontemporal_store(
                    rb[c], &outp[(size_t)((JPT - 1) * 8 + c) * NPTS]);
        }
    } else {
        const float* feat = (const float*)featv;
#pragma unroll 1
        for (int c = 0; c < JPT * 8; ++c) {
            float a = 0.0f;
#pragma unroll
            for (int k = 0; k < K_; ++k) {
                if (!val[k]) continue;
                const float* pb = feat + off[k] + (size_t)(cs * JPT * 8 + c) * P_;
                a += w00[k] * pb[0] + w01[k] * pb[dX[k]]
                   + w10[k] * pb[dY[k]] + w11[k] * pb[dX[k] + dY[k]];
            }
            __builtin_nontemporal_store(a, &outp[(size_t)c * NPTS]);
        }
    }
}

extern "C" void kernel_launch(void* const* d_in, const int* in_sizes, int n_in,
                              void* d_out, int out_size, void* d_ws, size_t ws_size,
                              hipStream_t stream) {
    const float* features   = (const float*)d_in[0];
    const float* intrinsics = (const float*)d_in[1];
    const float* extrinsics = (const float*)d_in[2];
    float* out = (float*)d_out;

    const size_t need = sizeof(uint4) * (size_t)BK_ * C8_ * P_;  // ~17 MB
    if (ws_size >= need) {
        uint4* featT = (uint4*)d_ws;
        shuffle_feat_f16<<<dim3(P_ / 64, BK_), 256, 0, stream>>>(features, featT);
        bev_project<true><<<dim3(256, B_, CSPLIT), 256, 0, stream>>>(
            (const void*)featT, intrinsics, extrinsics, out);
    } else {
        bev_project<false><<<dim3(256, B_, CSPLIT), 256, 0, stream>>>(
            (const void*)features, intrinsics, extrinsics, out);
    }
}